// Round 10
// baseline (239.516 us; speedup 1.0000x reference)
//
#include <hip/hip_runtime.h>
#include <hip/hip_bf16.h>

typedef __hip_bfloat16 bf16;
typedef __attribute__((ext_vector_type(8))) short short8;
typedef __attribute__((ext_vector_type(4))) float f32x4;
typedef __attribute__((ext_vector_type(16))) float f32x16;

__device__ __forceinline__ float b2f(bf16 v) { return __bfloat162float(v); }
__device__ __forceinline__ bf16  f2b(float v) { return __float2bfloat16(v); }

__device__ __forceinline__ unsigned cvt_pk_bf16(float lo, float hi) {
    unsigned r;
    asm("v_cvt_pk_bf16_f32 %0, %1, %2" : "=v"(r) : "v"(lo), "v"(hi));
    return r;
}

// ---------------------------------------------------------------------------
// Kernel A: fused weight-convert (blocks 0..1023) + GN partial sums
// (blocks 1024..1535).
// ---------------------------------------------------------------------------
__global__ __launch_bounds__(256) void pre_kernel(
    const float* __restrict__ wq, const float* __restrict__ wp,
    bf16* __restrict__ wqb, bf16* __restrict__ wpb,
    const float* __restrict__ x,
    float* __restrict__ partS, float* __restrict__ partQ)
{
    const int bid = blockIdx.x;
    const int t = threadIdx.x;
    if (bid < 1024) {
        int ch = bid * 256 + t;
        float4 v;
        bf16* dst;
        if (ch < 196608) {
            v = ((const float4*)wq)[ch];
            dst = wqb + ch * 4;
        } else {
            int c2 = ch - 196608;
            v = ((const float4*)wp)[c2];
            dst = wpb + c2 * 4;
        }
        bf16 o[4] = {f2b(v.x), f2b(v.y), f2b(v.z), f2b(v.w)};
        *(uint2*)dst = *(const uint2*)o;
        return;
    }
    const int pb = bid - 1024;              // 0..511
    const size_t base = (size_t)pb * 16384;

    float sum = 0.f, ssq = 0.f;
    const float4* x4 = (const float4*)(x + base);
    for (int i = t; i < 4096; i += 256) {
        float4 v = x4[i];
        sum += v.x + v.y + v.z + v.w;
        ssq += v.x * v.x + v.y * v.y + v.z * v.z + v.w * v.w;
    }
    #pragma unroll
    for (int off = 32; off > 0; off >>= 1) {
        sum += __shfl_down(sum, off);
        ssq += __shfl_down(ssq, off);
    }
    __shared__ float red[8];
    const int wid = t >> 6, lane = t & 63;
    if (lane == 0) { red[wid] = sum; red[4 + wid] = ssq; }
    __syncthreads();
    if (t == 0) {
        partS[pb] = red[0] + red[1] + red[2] + red[3];
        partQ[pb] = red[4] + red[5] + red[6] + red[7];
    }
}

// ---------------------------------------------------------------------------
// Kernel B: GN finalize (inlined per block) + apply + transpose:
// x[b,c,l] f32 -> Xt[b,l,c] bf16. Each block's 64-channel tile == one group.
// ---------------------------------------------------------------------------
__global__ __launch_bounds__(256) void gn_apply_t_kernel(
    const float* __restrict__ x,
    const float* __restrict__ partS, const float* __restrict__ partQ,
    const float* __restrict__ gamma, const float* __restrict__ beta,
    bf16* __restrict__ Xt)          // [16,1024,512]
{
    const int lt = blockIdx.x, ct = blockIdx.y, b = blockIdx.z;
    const int l0 = lt * 64, c0 = ct * 64;
    const int t = threadIdx.x;
    __shared__ float Ls[64][65];

    const int bg = b * 8 + ct;              // group == ct
    float s = partS[bg * 4] + partS[bg * 4 + 1] + partS[bg * 4 + 2] + partS[bg * 4 + 3];
    float q = partQ[bg * 4] + partQ[bg * 4 + 1] + partQ[bg * 4 + 2] + partQ[bg * 4 + 3];
    float mean = s * (1.f / 65536.f);
    float var  = q * (1.f / 65536.f) - mean * mean;
    float rstd = rsqrtf(var + 1e-5f);

    const float* xb = x + ((size_t)b * 512 + c0) * 1024 + l0;
    for (int i = t; i < 1024; i += 256) {
        int cc = i >> 4, lc = (i & 15) * 4;
        float4 v = *(const float4*)(xb + (size_t)cc * 1024 + lc);
        float sc = rstd * gamma[c0 + cc];
        float sh = beta[c0 + cc] - mean * sc;
        Ls[cc][lc]     = v.x * sc + sh;
        Ls[cc][lc + 1] = v.y * sc + sh;
        Ls[cc][lc + 2] = v.z * sc + sh;
        Ls[cc][lc + 3] = v.w * sc + sh;
    }
    __syncthreads();
    for (int i = t; i < 1024; i += 256) {
        int l = i >> 4, cc = (i & 15) * 4;
        bf16 o[4] = {f2b(Ls[cc][l]), f2b(Ls[cc + 1][l]),
                     f2b(Ls[cc + 2][l]), f2b(Ls[cc + 3][l])};
        *(uint2*)(Xt + ((size_t)b * 1024 + l0 + l) * 512 + c0 + cc) = *(const uint2*)o;
    }
}

// ---------------------------------------------------------------------------
// Kernel 3: QKV MFMA GEMM, 128x128 tile, BK=64 (verified round 8).
//   m-tiles 0-3 -> Qt[b][h][l][d], 4-7 -> Kt[b][h][m][d], 8-11 -> Vb[b][d][l]
// ---------------------------------------------------------------------------
__global__ __launch_bounds__(256) void mfma_qkv_kernel(
    const bf16* __restrict__ W,     // [1536,512]
    const bf16* __restrict__ Xt,    // [16,1024,512]
    const float* __restrict__ bias, // [1536]
    bf16* __restrict__ Qt,          // [16,4,1024,128]
    bf16* __restrict__ Kt,          // [16,4,1024,128]
    bf16* __restrict__ Vb)          // [16,512,1024]
{
    const int n0 = blockIdx.x * 128;
    const int m0 = blockIdx.y * 128;
    const int b  = blockIdx.z;
    const int t  = threadIdx.x;
    const int w  = t >> 6, lane = t & 63;
    const int c  = lane & 15, quad = lane >> 4;
    const int w0 = w & 1, w1 = w >> 1;
    const int ak = quad * 8;

    __shared__ __align__(16) bf16 smem[18432];
    bf16* As = smem;                // [128][72]
    bf16* Bs = smem + 9216;         // [128][72]
    bf16* Cs = smem;                // [128][136] (epilogue reuse)

    const bf16* Ag = W + (size_t)m0 * 512;
    const bf16* Bg = Xt + ((size_t)b * 1024 + n0) * 512;

    const int srow = t >> 3, skc = (t & 7) * 8;   // 32-row base, 64-col chunks

    short8 areg[4], breg[4];
    #pragma unroll
    for (int p = 0; p < 4; p++) {
        int row = srow + p * 32;
        areg[p] = *(const short8*)(Ag + (size_t)row * 512 + skc);
        breg[p] = *(const short8*)(Bg + (size_t)row * 512 + skc);
    }

    f32x4 acc[4][4];
    #pragma unroll
    for (int i = 0; i < 4; i++)
        #pragma unroll
        for (int j = 0; j < 4; j++)
            #pragma unroll
            for (int r = 0; r < 4; r++) acc[i][j][r] = 0.f;

    for (int k0 = 0; k0 < 512; k0 += 64) {
        __syncthreads();
        #pragma unroll
        for (int p = 0; p < 4; p++) {
            int row = srow + p * 32;
            *(short8*)&As[row * 72 + skc] = areg[p];
            *(short8*)&Bs[row * 72 + skc] = breg[p];
        }
        __syncthreads();
        {
            int k1 = (k0 + 64) & 511;
            #pragma unroll
            for (int p = 0; p < 4; p++) {
                int row = srow + p * 32;
                areg[p] = *(const short8*)(Ag + (size_t)row * 512 + k1 + skc);
                breg[p] = *(const short8*)(Bg + (size_t)row * 512 + k1 + skc);
            }
        }
        #pragma unroll
        for (int kk = 0; kk < 2; kk++) {
            short8 af[4], bf[4];
            #pragma unroll
            for (int jm = 0; jm < 4; jm++)
                af[jm] = *(const short8*)&As[(w0 * 64 + jm * 16 + c) * 72 + kk * 32 + ak];
            #pragma unroll
            for (int jn = 0; jn < 4; jn++)
                bf[jn] = *(const short8*)&Bs[(w1 * 64 + jn * 16 + c) * 72 + kk * 32 + ak];
            #pragma unroll
            for (int jm = 0; jm < 4; jm++)
                #pragma unroll
                for (int jn = 0; jn < 4; jn++)
                    acc[jm][jn] = __builtin_amdgcn_mfma_f32_16x16x32_bf16(
                        af[jm], bf[jn], acc[jm][jn], 0, 0, 0);
        }
    }

    __syncthreads();
    const int cls = m0 >> 9;        // 0=Q, 1=K, 2=V
    if (cls < 2) {
        #pragma unroll
        for (int jm = 0; jm < 4; jm++) {
            #pragma unroll
            for (int jn = 0; jn < 4; jn++) {
                bf16 o4[4];
                #pragma unroll
                for (int r = 0; r < 4; r++) {
                    int orow = w0 * 64 + jm * 16 + quad * 4 + r;
                    o4[r] = f2b(acc[jm][jn][r] + bias[m0 + orow]);
                }
                *(uint2*)&Cs[(size_t)(w1 * 64 + jn * 16 + c) * 136
                             + w0 * 64 + jm * 16 + quad * 4] = *(const uint2*)o4;
            }
        }
        __syncthreads();
        const int head = (m0 >> 7) & 3;
        bf16* Db = (cls == 0 ? Qt : Kt)
                   + (((size_t)(b * 4 + head)) * 1024 + n0) * 128;
        for (int i = t; i < 2048; i += 256) {
            int row = i >> 4, ch = (i & 15) * 8;
            *(short8*)(Db + (size_t)row * 128 + ch) = *(const short8*)&Cs[row * 136 + ch];
        }
    } else {
        #pragma unroll
        for (int jm = 0; jm < 4; jm++) {
            #pragma unroll
            for (int r = 0; r < 4; r++) {
                int orow = w0 * 64 + jm * 16 + quad * 4 + r;
                float bs = bias[m0 + orow];
                #pragma unroll
                for (int jn = 0; jn < 4; jn++)
                    Cs[orow * 136 + w1 * 64 + jn * 16 + c] = f2b(acc[jm][jn][r] + bs);
            }
        }
        __syncthreads();
        bf16* Cb = Vb + ((size_t)b * 512 + (m0 - 1024)) * 1024 + n0;
        for (int i = t; i < 2048; i += 256) {
            int row = i >> 4, ch = (i & 15) * 8;
            *(short8*)(Cb + (size_t)row * 1024 + ch) = *(const short8*)&Cs[row * 136 + ch];
        }
    }
}

// ---------------------------------------------------------------------------
// Kernel 4: MFMA flash attention. Round-5 verified math; K fragments now
// loaded DIRECT from global (L2-hot: 8 qt-blocks per (b,h) on same XCD) with
// the swap23 row permutation folded into per-lane addressing (involution:
// reading permuted slot r == loading physical row swap23(r)). Removes per
// wave-iter: 16 LDS reads + 4 LDS writes + 4 staging loads. kreg[2][8] uses
// the VGPR slack that grid-limited occupancy (2 waves/SIMD) makes free.
// V path / softmax / PV / epilogue byte-identical to round-5.
// ---------------------------------------------------------------------------
#define HD 128
#define QT 128
#define MT 64

__global__ __launch_bounds__(256, 2) void attn_mfma_kernel(
    const bf16* __restrict__ Qt,    // [16,4,1024,128]
    const bf16* __restrict__ Kt,    // [16,4,1024,128]
    const bf16* __restrict__ Vb,    // [16,512,1024]
    bf16* __restrict__ out)         // [16,1024,512]
{
    const int bh = blockIdx.x;      // 0..63
    const int qt = blockIdx.y;      // 0..7
    const int b = bh >> 2, h = bh & 3;
    const int t = threadIdx.x;      // 0..255
    const int w = t >> 6, lane = t & 63;
    const int wrow = lane & 31;
    const int blk  = lane >> 5;
    const int l0 = qt * QT;

    // LDS: Vs[128][72] in loop; epilogue Os[128][136] needs full 35840 B
    __shared__ __align__(16) bf16 smem[17920];

    // Q fragments: wave w owns q-rows [w*32, w*32+32)
    const int qrow = w * 32 + wrow;
    const bf16* Qr = Qt + (((size_t)(b * 4 + h)) * 1024 + l0 + qrow) * 128;
    short8 aq[8];
    #pragma unroll
    for (int kt = 0; kt < 8; kt++)
        aq[kt] = *(const short8*)(Qr + kt * 16 + blk * 8);

    const bf16* Kb = Kt + (((size_t)(b * 4 + h)) * 1024) * 128;
    const bf16* Vg = Vb + ((size_t)(b * 512 + h * HD)) * 1024;

    bf16* Vs = smem;            // [128][72]

    // K per-lane fragment bases: lane supplies permuted row r = nt*32+wrow,
    // physical row = swap23(r) (bits 2<->3 swapped; involution of the
    // verified LDS-staging permutation).
    const bf16* KpN[2];
    #pragma unroll
    for (int nt = 0; nt < 2; nt++) {
        int r = nt * 32 + wrow;
        int mphys = (r & 51) | ((r & 4) << 1) | ((r & 8) >> 1);
        KpN[nt] = Kb + (size_t)mphys * 128 + blk * 8;
    }

    // prologue: K fragments for mt=0, V staging regs for mt=0
    short8 kreg[2][8];
    #pragma unroll
    for (int nt = 0; nt < 2; nt++)
        #pragma unroll
        for (int kt = 0; kt < 8; kt++)
            kreg[nt][kt] = *(const short8*)(KpN[nt] + kt * 16);

    short8 vreg[4];
    #pragma unroll
    for (int p = 0; p < 4; p++) {
        int i = t + p * 256;
        vreg[p] = *(const short8*)(Vg + (size_t)(i >> 3) * 1024 + (i & 7) * 8);
    }

    f32x16 acc_o[4];
    #pragma unroll
    for (int n = 0; n < 4; n++)
        #pragma unroll
        for (int r = 0; r < 16; r++) acc_o[n][r] = 0.f;

    float psl4[4] = {0.f, 0.f, 0.f, 0.f};

    // exp(s*scale - 6) = exp2(s*kSc - kSh)
    const float kSc = 0.08838834764831845f * 1.4426950408889634f;
    const float kSh = 6.0f * 1.4426950408889634f;

    for (int mt = 0; mt < 1024 / MT; mt++) {
        __syncthreads();    // prev iter's Vs reads done
        #pragma unroll
        for (int p = 0; p < 4; p++) {
            int i = t + p * 256;
            *(short8*)&Vs[(i >> 3) * 72 + (i & 7) * 8] = vreg[p];
        }
        __syncthreads();    // Vs visible

        {   // prefetch next V tile (wraps harmlessly on last iter)
            int m0n = (mt < 15) ? (mt + 1) * MT : 0;
            #pragma unroll
            for (int p = 0; p < 4; p++) {
                int i = t + p * 256;
                vreg[p] = *(const short8*)(Vg + (size_t)(i >> 3) * 1024 + m0n + (i & 7) * 8);
            }
        }

        // ---- S^T = K Q^T : 2 m-tiles (32 each) x 8 k-steps, K from regs
        f32x16 accs[2];
        #pragma unroll
        for (int n = 0; n < 2; n++)
            #pragma unroll
            for (int r = 0; r < 16; r++) accs[n][r] = 0.f;
        __builtin_amdgcn_s_setprio(1);
        #pragma unroll
        for (int kt = 0; kt < 8; kt++) {
            #pragma unroll
            for (int nt = 0; nt < 2; nt++)
                accs[nt] = __builtin_amdgcn_mfma_f32_32x32x16_bf16(
                    kreg[nt][kt], aq[kt], accs[nt], 0, 0, 0);
        }
        __builtin_amdgcn_s_setprio(0);

        {   // prefetch next K fragments (kreg consumed; latency hidden
            // under softmax + PV + next barrier)
            int m0n = (mt < 15) ? (mt + 1) * MT : 0;
            #pragma unroll
            for (int nt = 0; nt < 2; nt++)
                #pragma unroll
                for (int kt = 0; kt < 8; kt++)
                    kreg[nt][kt] = *(const short8*)(KpN[nt] + (size_t)m0n * 128 + kt * 16);
        }

        // ---- softmax numerator, packed to bf16 PV fragments in-register
        unsigned pw[2][8];
        #pragma unroll
        for (int nt = 0; nt < 2; nt++) {
            float pv[16];
            #pragma unroll
            for (int r = 0; r < 16; r++)
                pv[r] = exp2f(accs[nt][r] * kSc - kSh);
            #pragma unroll
            for (int r = 0; r < 16; r++) psl4[r & 3] += pv[r];
            #pragma unroll
            for (int wd = 0; wd < 8; wd++)
                pw[nt][wd] = cvt_pk_bf16(pv[2 * wd], pv[2 * wd + 1]);
        }

        // ---- PV: O += P V^T (P fragments direct from regs)
        __builtin_amdgcn_s_setprio(1);
        #pragma unroll
        for (int kt2 = 0; kt2 < 4; kt2++) {
            union { short8 s; unsigned u[4]; } pa;
            #pragma unroll
            for (int wd = 0; wd < 4; wd++)
                pa.u[wd] = pw[kt2 >> 1][(kt2 & 1) * 4 + wd];
            #pragma unroll
            for (int nt2 = 0; nt2 < 4; nt2++) {
                short8 bv = *(const short8*)&Vs[(nt2 * 32 + wrow) * 72 + kt2 * 16 + blk * 8];
                acc_o[nt2] = __builtin_amdgcn_mfma_f32_32x32x16_bf16(pa.s, bv, acc_o[nt2], 0, 0, 0);
            }
        }
        __builtin_amdgcn_s_setprio(0);
    }

    // ---- epilogue: per-q totals live at lane wrow=q (both halves after xor)
    float psl = (psl4[0] + psl4[1]) + (psl4[2] + psl4[3]);
    float tot = psl + __shfl_xor(psl, 32);
    float inv[16];
    #pragma unroll
    for (int r = 0; r < 16; r++) {
        int q = (r & 3) + 8 * (r >> 2) + 4 * blk;
        inv[r] = __builtin_amdgcn_rcpf(__shfl(tot, q | (lane & 32)));
    }

    __syncthreads();                    // last iter's Vs reads done (all waves)
    bf16* Os = smem;                    // [128][136] = 34816 B
    #pragma unroll
    for (int nt2 = 0; nt2 < 4; nt2++)
        #pragma unroll
        for (int r = 0; r < 16; r++) {
            int row = w * 32 + (r & 3) + 8 * (r >> 2) + 4 * blk;
            Os[row * 136 + nt2 * 32 + wrow] = f2b(acc_o[nt2][r] * inv[r]);
        }
    __syncthreads();
    bf16* Ob = out + ((size_t)b * 1024 + l0) * 512 + h * HD;
    for (int i = t; i < 2048; i += 256) {
        int row = i >> 4, ch = (i & 15) * 8;
        *(short8*)(Ob + (size_t)row * 512 + ch) = *(const short8*)&Os[row * 136 + ch];
    }
}

// ---------------------------------------------------------------------------
// Kernel 5: proj GEMM + bias + residual, f32 out. BK=64 (verified round 9).
// ---------------------------------------------------------------------------
__global__ __launch_bounds__(256) void mfma_proj_kernel(
    const bf16* __restrict__ W,     // [512,512]
    const bf16* __restrict__ Xt,    // [16,1024,512] (attn_t)
    const float* __restrict__ bias, // [512]
    const float* __restrict__ res,  // [16,512,1024]
    float* __restrict__ C)          // [16,512,1024]
{
    const int n0 = blockIdx.x * 128;
    const int m0 = blockIdx.y * 128;
    const int b  = blockIdx.z;
    const int t  = threadIdx.x;
    const int w  = t >> 6, lane = t & 63;
    const int c  = lane & 15, quad = lane >> 4;
    const int w0 = w & 1, w1 = w >> 1;
    const int ak = quad * 8;

    __shared__ __align__(16) bf16 smem[18432];
    bf16* As = smem;                // [128][72]
    bf16* Bs = smem + 9216;         // [128][72]
    bf16* Cs = smem;                // [128][136] (epilogue reuse)

    const bf16* Ag = W + (size_t)m0 * 512;
    const bf16* Bg = Xt + ((size_t)b * 1024 + n0) * 512;

    const int srow = t >> 3, skc = (t & 7) * 8;

    short8 areg[4], breg[4];
    #pragma unroll
    for (int p = 0; p < 4; p++) {
        int row = srow + p * 32;
        areg[p] = *(const short8*)(Ag + (size_t)row * 512 + skc);
        breg[p] = *(const short8*)(Bg + (size_t)row * 512 + skc);
    }

    f32x4 acc[4][4];
    #pragma unroll
    for (int i = 0; i < 4; i++)
        #pragma unroll
        for (int j = 0; j < 4; j++)
            #pragma unroll
            for (int r = 0; r < 4; r++) acc[i][j][r] = 0.f;

    for (int k0 = 0; k0 < 512; k0 += 64) {
        __syncthreads();
        #pragma unroll
        for (int p = 0; p < 4; p++) {
            int row = srow + p * 32;
            *(short8*)&As[row * 72 + skc] = areg[p];
            *(short8*)&Bs[row * 72 + skc] = breg[p];
        }
        __syncthreads();
        {
            int k1 = (k0 + 64) & 511;
            #pragma unroll
            for (int p = 0; p < 4; p++) {
                int row = srow + p * 32;
                areg[p] = *(const short8*)(Ag + (size_t)row * 512 + k1 + skc);
                breg[p] = *(const short8*)(Bg + (size_t)row * 512 + k1 + skc);
            }
        }
        #pragma unroll
        for (int kk = 0; kk < 2; kk++) {
            short8 af[4], bf[4];
            #pragma unroll
            for (int jm = 0; jm < 4; jm++)
                af[jm] = *(const short8*)&As[(w0 * 64 + jm * 16 + c) * 72 + kk * 32 + ak];
            #pragma unroll
            for (int jn = 0; jn < 4; jn++)
                bf[jn] = *(const short8*)&Bs[(w1 * 64 + jn * 16 + c) * 72 + kk * 32 + ak];
            #pragma unroll
            for (int jm = 0; jm < 4; jm++)
                #pragma unroll
                for (int jn = 0; jn < 4; jn++)
                    acc[jm][jn] = __builtin_amdgcn_mfma_f32_16x16x32_bf16(
                        af[jm], bf[jn], acc[jm][jn], 0, 0, 0);
        }
    }

    __syncthreads();
    #pragma unroll
    for (int jm = 0; jm < 4; jm++) {
        #pragma unroll
        for (int r = 0; r < 4; r++) {
            int orow = w0 * 64 + jm * 16 + quad * 4 + r;
            float bs = bias[m0 + orow];
            #pragma unroll
            for (int jn = 0; jn < 4; jn++)
                Cs[orow * 136 + w1 * 64 + jn * 16 + c] = f2b(acc[jm][jn][r] + bs);
        }
    }
    __syncthreads();
    const float* Rb = res + ((size_t)b * 512 + m0) * 1024 + n0;
    float* Cb = C + ((size_t)b * 512 + m0) * 1024 + n0;
    for (int i = t; i < 4096; i += 256) {
        int row = i >> 5, ch = (i & 31) * 4;
        float4 rv = *(const float4*)(Rb + (size_t)row * 1024 + ch);
        float4 ov;
        ov.x = b2f(Cs[row * 136 + ch + 0]) + rv.x;
        ov.y = b2f(Cs[row * 136 + ch + 1]) + rv.y;
        ov.z = b2f(Cs[row * 136 + ch + 2]) + rv.z;
        ov.w = b2f(Cs[row * 136 + ch + 3]) + rv.w;
        *(float4*)(Cb + (size_t)row * 1024 + ch) = ov;
    }
}

// ---------------------------------------------------------------------------
extern "C" void kernel_launch(void* const* d_in, const int* in_sizes, int n_in,
                              void* d_out, int out_size, void* d_ws, size_t ws_size,
                              hipStream_t stream)
{
    const float* x      = (const float*)d_in[0];
    const float* gamma  = (const float*)d_in[1];
    const float* beta   = (const float*)d_in[2];
    const float* w_qkv  = (const float*)d_in[3];
    const float* b_qkv  = (const float*)d_in[4];
    const float* w_proj = (const float*)d_in[5];
    const float* b_proj = (const float*)d_in[6];
    float* out = (float*)d_out;

    char* ws = (char*)d_ws;
    bf16*  wqb    = (bf16*)(ws + 65536);                      // 1.5 MB
    bf16*  wpb    = (bf16*)(ws + 65536 + 1572864);            // 0.5 MB
    char*  big    = ws + 65536 + 2097152;
    bf16*  Xt     = (bf16*)(big);                             // 16 MB [16,1024,512]
    bf16*  Qt     = (bf16*)(big + (size_t)16777216);          // 16 MB [16,4,1024,128]
    bf16*  Kt     = (bf16*)(big + (size_t)2 * 16777216);      // 16 MB
    bf16*  Vb     = (bf16*)(big + (size_t)3 * 16777216);      // 16 MB [16,512,1024]
    float* partS  = (float*)(big + (size_t)4 * 16777216);     // 2 KB
    float* partQ  = partS + 512;                              // 2 KB
    bf16*  attn_t = Xt;   // Xt dead after qkv GEMM; attention writes here

    hipLaunchKernelGGL(pre_kernel, dim3(1536), dim3(256), 0, stream,
                       w_qkv, w_proj, wqb, wpb, x, partS, partQ);
    hipLaunchKernelGGL(gn_apply_t_kernel, dim3(16, 8, 16), dim3(256), 0, stream,
                       x, partS, partQ, gamma, beta, Xt);
    hipLaunchKernelGGL(mfma_qkv_kernel, dim3(8, 12, 16), dim3(256), 0, stream,
                       wqb, Xt, b_qkv, Qt, Kt, Vb);
    hipLaunchKernelGGL(attn_mfma_kernel, dim3(64, 8), dim3(256), 0, stream,
                       Qt, Kt, Vb, attn_t);
    hipLaunchKernelGGL(mfma_proj_kernel, dim3(8, 4, 16), dim3(256), 0, stream,
                       wpb, attn_t, b_proj, x, out);
}

// Round 11
// 216.325 us; speedup vs baseline: 1.1072x; 1.1072x over previous
//
#include <hip/hip_runtime.h>
#include <hip/hip_bf16.h>

typedef __hip_bfloat16 bf16;
typedef __attribute__((ext_vector_type(8))) short short8;
typedef __attribute__((ext_vector_type(4))) float f32x4;
typedef __attribute__((ext_vector_type(16))) float f32x16;

__device__ __forceinline__ float b2f(bf16 v) { return __bfloat162float(v); }
__device__ __forceinline__ bf16  f2b(float v) { return __float2bfloat16(v); }

__device__ __forceinline__ unsigned cvt_pk_bf16(float lo, float hi) {
    unsigned r;
    asm("v_cvt_pk_bf16_f32 %0, %1, %2" : "=v"(r) : "v"(lo), "v"(hi));
    return r;
}

// ---------------------------------------------------------------------------
// Kernel A: fused weight-convert (blocks 0..1023) + GN partial sums
// (blocks 1024..1535).
// ---------------------------------------------------------------------------
__global__ __launch_bounds__(256) void pre_kernel(
    const float* __restrict__ wq, const float* __restrict__ wp,
    bf16* __restrict__ wqb, bf16* __restrict__ wpb,
    const float* __restrict__ x,
    float* __restrict__ partS, float* __restrict__ partQ)
{
    const int bid = blockIdx.x;
    const int t = threadIdx.x;
    if (bid < 1024) {
        int ch = bid * 256 + t;
        float4 v;
        bf16* dst;
        if (ch < 196608) {
            v = ((const float4*)wq)[ch];
            dst = wqb + ch * 4;
        } else {
            int c2 = ch - 196608;
            v = ((const float4*)wp)[c2];
            dst = wpb + c2 * 4;
        }
        bf16 o[4] = {f2b(v.x), f2b(v.y), f2b(v.z), f2b(v.w)};
        *(uint2*)dst = *(const uint2*)o;
        return;
    }
    const int pb = bid - 1024;              // 0..511
    const size_t base = (size_t)pb * 16384;

    float sum = 0.f, ssq = 0.f;
    const float4* x4 = (const float4*)(x + base);
    for (int i = t; i < 4096; i += 256) {
        float4 v = x4[i];
        sum += v.x + v.y + v.z + v.w;
        ssq += v.x * v.x + v.y * v.y + v.z * v.z + v.w * v.w;
    }
    #pragma unroll
    for (int off = 32; off > 0; off >>= 1) {
        sum += __shfl_down(sum, off);
        ssq += __shfl_down(ssq, off);
    }
    __shared__ float red[8];
    const int wid = t >> 6, lane = t & 63;
    if (lane == 0) { red[wid] = sum; red[4 + wid] = ssq; }
    __syncthreads();
    if (t == 0) {
        partS[pb] = red[0] + red[1] + red[2] + red[3];
        partQ[pb] = red[4] + red[5] + red[6] + red[7];
    }
}

// ---------------------------------------------------------------------------
// Kernel B: GN finalize (inlined per block) + apply + transpose:
// x[b,c,l] f32 -> Xt[b,l,c] bf16. Each block's 64-channel tile == one group.
// ---------------------------------------------------------------------------
__global__ __launch_bounds__(256) void gn_apply_t_kernel(
    const float* __restrict__ x,
    const float* __restrict__ partS, const float* __restrict__ partQ,
    const float* __restrict__ gamma, const float* __restrict__ beta,
    bf16* __restrict__ Xt)          // [16,1024,512]
{
    const int lt = blockIdx.x, ct = blockIdx.y, b = blockIdx.z;
    const int l0 = lt * 64, c0 = ct * 64;
    const int t = threadIdx.x;
    __shared__ float Ls[64][65];

    const int bg = b * 8 + ct;              // group == ct
    float s = partS[bg * 4] + partS[bg * 4 + 1] + partS[bg * 4 + 2] + partS[bg * 4 + 3];
    float q = partQ[bg * 4] + partQ[bg * 4 + 1] + partQ[bg * 4 + 2] + partQ[bg * 4 + 3];
    float mean = s * (1.f / 65536.f);
    float var  = q * (1.f / 65536.f) - mean * mean;
    float rstd = rsqrtf(var + 1e-5f);

    const float* xb = x + ((size_t)b * 512 + c0) * 1024 + l0;
    for (int i = t; i < 1024; i += 256) {
        int cc = i >> 4, lc = (i & 15) * 4;
        float4 v = *(const float4*)(xb + (size_t)cc * 1024 + lc);
        float sc = rstd * gamma[c0 + cc];
        float sh = beta[c0 + cc] - mean * sc;
        Ls[cc][lc]     = v.x * sc + sh;
        Ls[cc][lc + 1] = v.y * sc + sh;
        Ls[cc][lc + 2] = v.z * sc + sh;
        Ls[cc][lc + 3] = v.w * sc + sh;
    }
    __syncthreads();
    for (int i = t; i < 1024; i += 256) {
        int l = i >> 4, cc = (i & 15) * 4;
        bf16 o[4] = {f2b(Ls[cc][l]), f2b(Ls[cc + 1][l]),
                     f2b(Ls[cc + 2][l]), f2b(Ls[cc + 3][l])};
        *(uint2*)(Xt + ((size_t)b * 1024 + l0 + l) * 512 + c0 + cc) = *(const uint2*)o;
    }
}

// ---------------------------------------------------------------------------
// Kernel 3: QKV MFMA GEMM, 128x128 tile, BK=64 (verified round 8).
//   m-tiles 0-3 -> Qt[b][h][l][d], 4-7 -> Kt[b][h][m][d], 8-11 -> Vb[b][d][l]
// ---------------------------------------------------------------------------
__global__ __launch_bounds__(256) void mfma_qkv_kernel(
    const bf16* __restrict__ W,     // [1536,512]
    const bf16* __restrict__ Xt,    // [16,1024,512]
    const float* __restrict__ bias, // [1536]
    bf16* __restrict__ Qt,          // [16,4,1024,128]
    bf16* __restrict__ Kt,          // [16,4,1024,128]
    bf16* __restrict__ Vb)          // [16,512,1024]
{
    const int n0 = blockIdx.x * 128;
    const int m0 = blockIdx.y * 128;
    const int b  = blockIdx.z;
    const int t  = threadIdx.x;
    const int w  = t >> 6, lane = t & 63;
    const int c  = lane & 15, quad = lane >> 4;
    const int w0 = w & 1, w1 = w >> 1;
    const int ak = quad * 8;

    __shared__ __align__(16) bf16 smem[18432];
    bf16* As = smem;                // [128][72]
    bf16* Bs = smem + 9216;         // [128][72]
    bf16* Cs = smem;                // [128][136] (epilogue reuse)

    const bf16* Ag = W + (size_t)m0 * 512;
    const bf16* Bg = Xt + ((size_t)b * 1024 + n0) * 512;

    const int srow = t >> 3, skc = (t & 7) * 8;   // 32-row base, 64-col chunks

    short8 areg[4], breg[4];
    #pragma unroll
    for (int p = 0; p < 4; p++) {
        int row = srow + p * 32;
        areg[p] = *(const short8*)(Ag + (size_t)row * 512 + skc);
        breg[p] = *(const short8*)(Bg + (size_t)row * 512 + skc);
    }

    f32x4 acc[4][4];
    #pragma unroll
    for (int i = 0; i < 4; i++)
        #pragma unroll
        for (int j = 0; j < 4; j++)
            #pragma unroll
            for (int r = 0; r < 4; r++) acc[i][j][r] = 0.f;

    for (int k0 = 0; k0 < 512; k0 += 64) {
        __syncthreads();
        #pragma unroll
        for (int p = 0; p < 4; p++) {
            int row = srow + p * 32;
            *(short8*)&As[row * 72 + skc] = areg[p];
            *(short8*)&Bs[row * 72 + skc] = breg[p];
        }
        __syncthreads();
        {
            int k1 = (k0 + 64) & 511;
            #pragma unroll
            for (int p = 0; p < 4; p++) {
                int row = srow + p * 32;
                areg[p] = *(const short8*)(Ag + (size_t)row * 512 + k1 + skc);
                breg[p] = *(const short8*)(Bg + (size_t)row * 512 + k1 + skc);
            }
        }
        #pragma unroll
        for (int kk = 0; kk < 2; kk++) {
            short8 af[4], bf[4];
            #pragma unroll
            for (int jm = 0; jm < 4; jm++)
                af[jm] = *(const short8*)&As[(w0 * 64 + jm * 16 + c) * 72 + kk * 32 + ak];
            #pragma unroll
            for (int jn = 0; jn < 4; jn++)
                bf[jn] = *(const short8*)&Bs[(w1 * 64 + jn * 16 + c) * 72 + kk * 32 + ak];
            #pragma unroll
            for (int jm = 0; jm < 4; jm++)
                #pragma unroll
                for (int jn = 0; jn < 4; jn++)
                    acc[jm][jn] = __builtin_amdgcn_mfma_f32_16x16x32_bf16(
                        af[jm], bf[jn], acc[jm][jn], 0, 0, 0);
        }
    }

    __syncthreads();
    const int cls = m0 >> 9;        // 0=Q, 1=K, 2=V
    if (cls < 2) {
        #pragma unroll
        for (int jm = 0; jm < 4; jm++) {
            #pragma unroll
            for (int jn = 0; jn < 4; jn++) {
                bf16 o4[4];
                #pragma unroll
                for (int r = 0; r < 4; r++) {
                    int orow = w0 * 64 + jm * 16 + quad * 4 + r;
                    o4[r] = f2b(acc[jm][jn][r] + bias[m0 + orow]);
                }
                *(uint2*)&Cs[(size_t)(w1 * 64 + jn * 16 + c) * 136
                             + w0 * 64 + jm * 16 + quad * 4] = *(const uint2*)o4;
            }
        }
        __syncthreads();
        const int head = (m0 >> 7) & 3;
        bf16* Db = (cls == 0 ? Qt : Kt)
                   + (((size_t)(b * 4 + head)) * 1024 + n0) * 128;
        for (int i = t; i < 2048; i += 256) {
            int row = i >> 4, ch = (i & 15) * 8;
            *(short8*)(Db + (size_t)row * 128 + ch) = *(const short8*)&Cs[row * 136 + ch];
        }
    } else {
        #pragma unroll
        for (int jm = 0; jm < 4; jm++) {
            #pragma unroll
            for (int r = 0; r < 4; r++) {
                int orow = w0 * 64 + jm * 16 + quad * 4 + r;
                float bs = bias[m0 + orow];
                #pragma unroll
                for (int jn = 0; jn < 4; jn++)
                    Cs[orow * 136 + w1 * 64 + jn * 16 + c] = f2b(acc[jm][jn][r] + bs);
            }
        }
        __syncthreads();
        bf16* Cb = Vb + ((size_t)b * 512 + (m0 - 1024)) * 1024 + n0;
        for (int i = t; i < 2048; i += 256) {
            int row = i >> 4, ch = (i & 15) * 8;
            *(short8*)(Cb + (size_t)row * 1024 + ch) = *(const short8*)&Cs[row * 136 + ch];
        }
    }
}

// ---------------------------------------------------------------------------
// Kernel 4: MFMA flash attention. QT=256, 512 threads / 8 waves, grid 64x4 =
// 256 blocks (1 block/CU). Per-wave code byte-identical to the verified
// round-9 kernel (wave w owns q-rows w*32..+32, full m-range, swap23 K
// staging, in-register P, per-wave psum); merging 2 blocks into 1 halves
// per-CU K/V staging traffic (round-10 lesson: LDS staging deduplicates
// operand reads across waves -- so stage once for MORE waves, never fewer).
// LDS 69632 B (epilogue Os[256][136]); loop uses first 35840 B (Ks+Vs).
// 69632 B also moves hipcc's VGPR budget above the 124 live set (no spill).
// ---------------------------------------------------------------------------
#define HD 128
#define QT 256
#define MT 64

__global__ __launch_bounds__(512, 2) void attn_mfma_kernel(
    const bf16* __restrict__ Qt,    // [16,4,1024,128]
    const bf16* __restrict__ Kt,    // [16,4,1024,128]
    const bf16* __restrict__ Vb,    // [16,512,1024]
    bf16* __restrict__ out)         // [16,1024,512]
{
    const int bh = blockIdx.x;      // 0..63 (XCD = bh % 8; all qt same XCD)
    const int qt = blockIdx.y;      // 0..3
    const int b = bh >> 2, h = bh & 3;
    const int t = threadIdx.x;      // 0..511
    const int w = t >> 6, lane = t & 63;   // w = 0..7
    const int wrow = lane & 31;
    const int blk  = lane >> 5;
    const int l0 = qt * QT;

    // 69632 B: loop Ks[64][136]+Vs[128][72] = 35840 B; epilogue Os[256][136]
    __shared__ __align__(16) bf16 smem[34816];

    // Q fragments: wave w owns q-rows [w*32, w*32+32) of this 256-row block
    const int qrow = w * 32 + wrow;
    const bf16* Qr = Qt + (((size_t)(b * 4 + h)) * 1024 + l0 + qrow) * 128;
    short8 aq[8];
    #pragma unroll
    for (int kt = 0; kt < 8; kt++)
        aq[kt] = *(const short8*)(Qr + kt * 16 + blk * 8);

    const bf16* Kb = Kt + (((size_t)(b * 4 + h)) * 1024) * 128;
    const bf16* Vg = Vb + ((size_t)(b * 512 + h * HD)) * 1024;

    bf16* Ks = smem;            // [64][136]
    bf16* Vs = smem + 8704;     // [128][72]

    short8 kreg[2], vreg[2];
    #pragma unroll
    for (int p = 0; p < 2; p++) {
        int i = t + p * 512;
        kreg[p] = *(const short8*)(Kb + (size_t)(i >> 4) * 128 + (i & 15) * 8);
        vreg[p] = *(const short8*)(Vg + (size_t)(i >> 3) * 1024 + (i & 7) * 8);
    }

    f32x16 acc_o[4];
    #pragma unroll
    for (int n = 0; n < 4; n++)
        #pragma unroll
        for (int r = 0; r < 16; r++) acc_o[n][r] = 0.f;

    float psl4[4] = {0.f, 0.f, 0.f, 0.f};

    // exp(s*scale - 6) = exp2(s*kSc - kSh)
    const float kSc = 0.08838834764831845f * 1.4426950408889634f;
    const float kSh = 6.0f * 1.4426950408889634f;

    for (int mt = 0; mt < 1024 / MT; mt++) {
        __syncthreads();    // prev iter's LDS reads done
        #pragma unroll
        for (int p = 0; p < 2; p++) {
            int i = t + p * 512;
            int m = i >> 4;
            int mrow = (m & 51) | ((m & 4) << 1) | ((m & 8) >> 1);   // swap bits 2,3
            *(short8*)&Ks[mrow * 136 + (i & 15) * 8] = kreg[p];
            *(short8*)&Vs[(i >> 3) * 72 + (i & 7) * 8]  = vreg[p];
        }
        __syncthreads();    // LDS visible

        {   // prefetch next tile (wraps harmlessly on last iter)
            int m0n = (mt < 15) ? (mt + 1) * MT : 0;
            #pragma unroll
            for (int p = 0; p < 2; p++) {
                int i = t + p * 512;
                kreg[p] = *(const short8*)(Kb + (size_t)(m0n + (i >> 4)) * 128 + (i & 15) * 8);
                vreg[p] = *(const short8*)(Vg + (size_t)(i >> 3) * 1024 + m0n + (i & 7) * 8);
            }
        }

        // ---- S^T = K Q^T : 2 m-tiles (32 each) x 8 k-steps
        f32x16 accs[2];
        #pragma unroll
        for (int n = 0; n < 2; n++)
            #pragma unroll
            for (int r = 0; r < 16; r++) accs[n][r] = 0.f;
        __builtin_amdgcn_s_setprio(1);
        #pragma unroll
        for (int kt = 0; kt < 8; kt++) {
            #pragma unroll
            for (int nt = 0; nt < 2; nt++) {
                short8 afr = *(const short8*)&Ks[(nt * 32 + wrow) * 136 + kt * 16 + blk * 8];
                accs[nt] = __builtin_amdgcn_mfma_f32_32x32x16_bf16(afr, aq[kt], accs[nt], 0, 0, 0);
            }
        }
        __builtin_amdgcn_s_setprio(0);

        // ---- softmax numerator, packed to bf16 PV fragments in-register
        unsigned pw[2][8];
        #pragma unroll
        for (int nt = 0; nt < 2; nt++) {
            float pv[16];
            #pragma unroll
            for (int r = 0; r < 16; r++)
                pv[r] = exp2f(accs[nt][r] * kSc - kSh);
            #pragma unroll
            for (int r = 0; r < 16; r++) psl4[r & 3] += pv[r];
            #pragma unroll
            for (int wd = 0; wd < 8; wd++)
                pw[nt][wd] = cvt_pk_bf16(pv[2 * wd], pv[2 * wd + 1]);
        }

        // ---- PV: O += P V^T (P fragments direct from regs)
        __builtin_amdgcn_s_setprio(1);
        #pragma unroll
        for (int kt2 = 0; kt2 < 4; kt2++) {
            union { short8 s; unsigned u[4]; } pa;
            #pragma unroll
            for (int wd = 0; wd < 4; wd++)
                pa.u[wd] = pw[kt2 >> 1][(kt2 & 1) * 4 + wd];
            #pragma unroll
            for (int nt2 = 0; nt2 < 4; nt2++) {
                short8 bv = *(const short8*)&Vs[(nt2 * 32 + wrow) * 72 + kt2 * 16 + blk * 8];
                acc_o[nt2] = __builtin_amdgcn_mfma_f32_32x32x16_bf16(pa.s, bv, acc_o[nt2], 0, 0, 0);
            }
        }
        __builtin_amdgcn_s_setprio(0);
    }

    // ---- epilogue: per-q totals live at lane wrow=q (both halves after xor)
    float psl = (psl4[0] + psl4[1]) + (psl4[2] + psl4[3]);
    float tot = psl + __shfl_xor(psl, 32);
    float inv[16];
    #pragma unroll
    for (int r = 0; r < 16; r++) {
        int q = (r & 3) + 8 * (r >> 2) + 4 * blk;
        inv[r] = __builtin_amdgcn_rcpf(__shfl(tot, q | (lane & 32)));
    }

    __syncthreads();                    // last iter's Ks/Vs reads done (all waves)
    bf16* Os = smem;                    // [256][136] = 69632 B
    #pragma unroll
    for (int nt2 = 0; nt2 < 4; nt2++)
        #pragma unroll
        for (int r = 0; r < 16; r++) {
            int row = w * 32 + (r & 3) + 8 * (r >> 2) + 4 * blk;
            Os[row * 136 + nt2 * 32 + wrow] = f2b(acc_o[nt2][r] * inv[r]);
        }
    __syncthreads();
    bf16* Ob = out + ((size_t)b * 1024 + l0) * 512 + h * HD;
    for (int i = t; i < 4096; i += 512) {
        int row = i >> 4, ch = (i & 15) * 8;
        *(short8*)(Ob + (size_t)row * 512 + ch) = *(const short8*)&Os[row * 136 + ch];
    }
}

// ---------------------------------------------------------------------------
// Kernel 5: proj GEMM + bias + residual, f32 out. BK=64 (verified round 9).
// ---------------------------------------------------------------------------
__global__ __launch_bounds__(256) void mfma_proj_kernel(
    const bf16* __restrict__ W,     // [512,512]
    const bf16* __restrict__ Xt,    // [16,1024,512] (attn_t)
    const float* __restrict__ bias, // [512]
    const float* __restrict__ res,  // [16,512,1024]
    float* __restrict__ C)          // [16,512,1024]
{
    const int n0 = blockIdx.x * 128;
    const int m0 = blockIdx.y * 128;
    const int b  = blockIdx.z;
    const int t  = threadIdx.x;
    const int w  = t >> 6, lane = t & 63;
    const int c  = lane & 15, quad = lane >> 4;
    const int w0 = w & 1, w1 = w >> 1;
    const int ak = quad * 8;

    __shared__ __align__(16) bf16 smem[18432];
    bf16* As = smem;                // [128][72]
    bf16* Bs = smem + 9216;         // [128][72]
    bf16* Cs = smem;                // [128][136] (epilogue reuse)

    const bf16* Ag = W + (size_t)m0 * 512;
    const bf16* Bg = Xt + ((size_t)b * 1024 + n0) * 512;

    const int srow = t >> 3, skc = (t & 7) * 8;

    short8 areg[4], breg[4];
    #pragma unroll
    for (int p = 0; p < 4; p++) {
        int row = srow + p * 32;
        areg[p] = *(const short8*)(Ag + (size_t)row * 512 + skc);
        breg[p] = *(const short8*)(Bg + (size_t)row * 512 + skc);
    }

    f32x4 acc[4][4];
    #pragma unroll
    for (int i = 0; i < 4; i++)
        #pragma unroll
        for (int j = 0; j < 4; j++)
            #pragma unroll
            for (int r = 0; r < 4; r++) acc[i][j][r] = 0.f;

    for (int k0 = 0; k0 < 512; k0 += 64) {
        __syncthreads();
        #pragma unroll
        for (int p = 0; p < 4; p++) {
            int row = srow + p * 32;
            *(short8*)&As[row * 72 + skc] = areg[p];
            *(short8*)&Bs[row * 72 + skc] = breg[p];
        }
        __syncthreads();
        {
            int k1 = (k0 + 64) & 511;
            #pragma unroll
            for (int p = 0; p < 4; p++) {
                int row = srow + p * 32;
                areg[p] = *(const short8*)(Ag + (size_t)row * 512 + k1 + skc);
                breg[p] = *(const short8*)(Bg + (size_t)row * 512 + k1 + skc);
            }
        }
        #pragma unroll
        for (int kk = 0; kk < 2; kk++) {
            short8 af[4], bf[4];
            #pragma unroll
            for (int jm = 0; jm < 4; jm++)
                af[jm] = *(const short8*)&As[(w0 * 64 + jm * 16 + c) * 72 + kk * 32 + ak];
            #pragma unroll
            for (int jn = 0; jn < 4; jn++)
                bf[jn] = *(const short8*)&Bs[(w1 * 64 + jn * 16 + c) * 72 + kk * 32 + ak];
            #pragma unroll
            for (int jm = 0; jm < 4; jm++)
                #pragma unroll
                for (int jn = 0; jn < 4; jn++)
                    acc[jm][jn] = __builtin_amdgcn_mfma_f32_16x16x32_bf16(
                        af[jm], bf[jn], acc[jm][jn], 0, 0, 0);
        }
    }

    __syncthreads();
    #pragma unroll
    for (int jm = 0; jm < 4; jm++) {
        #pragma unroll
        for (int r = 0; r < 4; r++) {
            int orow = w0 * 64 + jm * 16 + quad * 4 + r;
            float bs = bias[m0 + orow];
            #pragma unroll
            for (int jn = 0; jn < 4; jn++)
                Cs[orow * 136 + w1 * 64 + jn * 16 + c] = f2b(acc[jm][jn][r] + bs);
        }
    }
    __syncthreads();
    const float* Rb = res + ((size_t)b * 512 + m0) * 1024 + n0;
    float* Cb = C + ((size_t)b * 512 + m0) * 1024 + n0;
    for (int i = t; i < 4096; i += 256) {
        int row = i >> 5, ch = (i & 31) * 4;
        float4 rv = *(const float4*)(Rb + (size_t)row * 1024 + ch);
        float4 ov;
        ov.x = b2f(Cs[row * 136 + ch + 0]) + rv.x;
        ov.y = b2f(Cs[row * 136 + ch + 1]) + rv.y;
        ov.z = b2f(Cs[row * 136 + ch + 2]) + rv.z;
        ov.w = b2f(Cs[row * 136 + ch + 3]) + rv.w;
        *(float4*)(Cb + (size_t)row * 1024 + ch) = ov;
    }
}

// ---------------------------------------------------------------------------
extern "C" void kernel_launch(void* const* d_in, const int* in_sizes, int n_in,
                              void* d_out, int out_size, void* d_ws, size_t ws_size,
                              hipStream_t stream)
{
    const float* x      = (const float*)d_in[0];
    const float* gamma  = (const float*)d_in[1];
    const float* beta   = (const float*)d_in[2];
    const float* w_qkv  = (const float*)d_in[3];
    const float* b_qkv  = (const float*)d_in[4];
    const float* w_proj = (const float*)d_in[5];
    const float* b_proj = (const float*)d_in[6];
    float* out = (float*)d_out;

    char* ws = (char*)d_ws;
    bf16*  wqb    = (bf16*)(ws + 65536);                      // 1.5 MB
    bf16*  wpb    = (bf16*)(ws + 65536 + 1572864);            // 0.5 MB
    char*  big    = ws + 65536 + 2097152;
    bf16*  Xt     = (bf16*)(big);                             // 16 MB [16,1024,512]
    bf16*  Qt     = (bf16*)(big + (size_t)16777216);          // 16 MB [16,4,1024,128]
    bf16*  Kt     = (bf16*)(big + (size_t)2 * 16777216);      // 16 MB
    bf16*  Vb     = (bf16*)(big + (size_t)3 * 16777216);      // 16 MB [16,512,1024]
    float* partS  = (float*)(big + (size_t)4 * 16777216);     // 2 KB
    float* partQ  = partS + 512;                              // 2 KB
    bf16*  attn_t = Xt;   // Xt dead after qkv GEMM; attention writes here

    hipLaunchKernelGGL(pre_kernel, dim3(1536), dim3(256), 0, stream,
                       w_qkv, w_proj, wqb, wpb, x, partS, partQ);
    hipLaunchKernelGGL(gn_apply_t_kernel, dim3(16, 8, 16), dim3(256), 0, stream,
                       x, partS, partQ, gamma, beta, Xt);
    hipLaunchKernelGGL(mfma_qkv_kernel, dim3(8, 12, 16), dim3(256), 0, stream,
                       wqb, Xt, b_qkv, Qt, Kt, Vb);
    hipLaunchKernelGGL(attn_mfma_kernel, dim3(64, 4), dim3(512), 0, stream,
                       Qt, Kt, Vb, attn_t);
    hipLaunchKernelGGL(mfma_proj_kernel, dim3(8, 4, 16), dim3(256), 0, stream,
                       wpb, attn_t, b_proj, x, out);
}

// Round 13
// 209.904 us; speedup vs baseline: 1.1411x; 1.0306x over previous
//
#include <hip/hip_runtime.h>
#include <hip/hip_bf16.h>

typedef __hip_bfloat16 bf16;
typedef __attribute__((ext_vector_type(8))) short short8;
typedef __attribute__((ext_vector_type(4))) float f32x4;
typedef __attribute__((ext_vector_type(16))) float f32x16;

__device__ __forceinline__ float b2f(bf16 v) { return __bfloat162float(v); }
__device__ __forceinline__ bf16  f2b(float v) { return __float2bfloat16(v); }

__device__ __forceinline__ unsigned cvt_pk_bf16(float lo, float hi) {
    unsigned r;
    asm("v_cvt_pk_bf16_f32 %0, %1, %2" : "=v"(r) : "v"(lo), "v"(hi));
    return r;
}

// Stage one 128x32 bf16 tile (8 KB) from global (row stride 512 el) into
// LINEAR LDS via global_load_lds width-16. Per-lane global address: each
// 4-lane group reads one contiguous 64 B row segment (coalesced, 1 KB/wave
// instr). LDS dest is wave-uniform base; HW appends lane*16 B, which lands
// element (lane>>2)*32 + (lane&3)*8 == row-major [row][32]. No swizzle:
// fragment reads at row*32 + quad*8 already hit the 8-dword/bank minimum.
__device__ __forceinline__ void stage_tile_gld(
    const bf16* __restrict__ gbase, bf16* lbuf, int t)
{
    const int lane = t & 63, w = t >> 6;
    #pragma unroll
    for (int p = 0; p < 2; p++) {
        int row = p * 64 + w * 16 + (lane >> 2);
        __builtin_amdgcn_global_load_lds(
            (const __attribute__((address_space(1))) void*)
                (gbase + (size_t)row * 512 + (lane & 3) * 8),
            (__attribute__((address_space(3))) void*)(lbuf + p * 2048 + w * 512),
            16, 0, 0);
    }
}

// ---------------------------------------------------------------------------
// Kernel A: fused weight-convert (blocks 0..1023) + GN partial sums
// (blocks 1024..1535).
// ---------------------------------------------------------------------------
__global__ __launch_bounds__(256) void pre_kernel(
    const float* __restrict__ wq, const float* __restrict__ wp,
    bf16* __restrict__ wqb, bf16* __restrict__ wpb,
    const float* __restrict__ x,
    float* __restrict__ partS, float* __restrict__ partQ)
{
    const int bid = blockIdx.x;
    const int t = threadIdx.x;
    if (bid < 1024) {
        int ch = bid * 256 + t;
        float4 v;
        bf16* dst;
        if (ch < 196608) {
            v = ((const float4*)wq)[ch];
            dst = wqb + ch * 4;
        } else {
            int c2 = ch - 196608;
            v = ((const float4*)wp)[c2];
            dst = wpb + c2 * 4;
        }
        bf16 o[4] = {f2b(v.x), f2b(v.y), f2b(v.z), f2b(v.w)};
        *(uint2*)dst = *(const uint2*)o;
        return;
    }
    const int pb = bid - 1024;              // 0..511
    const size_t base = (size_t)pb * 16384;

    float sum = 0.f, ssq = 0.f;
    const float4* x4 = (const float4*)(x + base);
    for (int i = t; i < 4096; i += 256) {
        float4 v = x4[i];
        sum += v.x + v.y + v.z + v.w;
        ssq += v.x * v.x + v.y * v.y + v.z * v.z + v.w * v.w;
    }
    #pragma unroll
    for (int off = 32; off > 0; off >>= 1) {
        sum += __shfl_down(sum, off);
        ssq += __shfl_down(ssq, off);
    }
    __shared__ float red[8];
    const int wid = t >> 6, lane = t & 63;
    if (lane == 0) { red[wid] = sum; red[4 + wid] = ssq; }
    __syncthreads();
    if (t == 0) {
        partS[pb] = red[0] + red[1] + red[2] + red[3];
        partQ[pb] = red[4] + red[5] + red[6] + red[7];
    }
}

// ---------------------------------------------------------------------------
// Kernel B: GN finalize (inlined per block) + apply + transpose:
// x[b,c,l] f32 -> Xt[b,l,c] bf16. Each block's 64-channel tile == one group.
// ---------------------------------------------------------------------------
__global__ __launch_bounds__(256) void gn_apply_t_kernel(
    const float* __restrict__ x,
    const float* __restrict__ partS, const float* __restrict__ partQ,
    const float* __restrict__ gamma, const float* __restrict__ beta,
    bf16* __restrict__ Xt)          // [16,1024,512]
{
    const int lt = blockIdx.x, ct = blockIdx.y, b = blockIdx.z;
    const int l0 = lt * 64, c0 = ct * 64;
    const int t = threadIdx.x;
    __shared__ float Ls[64][65];

    const int bg = b * 8 + ct;              // group == ct
    float s = partS[bg * 4] + partS[bg * 4 + 1] + partS[bg * 4 + 2] + partS[bg * 4 + 3];
    float q = partQ[bg * 4] + partQ[bg * 4 + 1] + partQ[bg * 4 + 2] + partQ[bg * 4 + 3];
    float mean = s * (1.f / 65536.f);
    float var  = q * (1.f / 65536.f) - mean * mean;
    float rstd = rsqrtf(var + 1e-5f);

    const float* xb = x + ((size_t)b * 512 + c0) * 1024 + l0;
    for (int i = t; i < 1024; i += 256) {
        int cc = i >> 4, lc = (i & 15) * 4;
        float4 v = *(const float4*)(xb + (size_t)cc * 1024 + lc);
        float sc = rstd * gamma[c0 + cc];
        float sh = beta[c0 + cc] - mean * sc;
        Ls[cc][lc]     = v.x * sc + sh;
        Ls[cc][lc + 1] = v.y * sc + sh;
        Ls[cc][lc + 2] = v.z * sc + sh;
        Ls[cc][lc + 3] = v.w * sc + sh;
    }
    __syncthreads();
    for (int i = t; i < 1024; i += 256) {
        int l = i >> 4, cc = (i & 15) * 4;
        bf16 o[4] = {f2b(Ls[cc][l]), f2b(Ls[cc + 1][l]),
                     f2b(Ls[cc + 2][l]), f2b(Ls[cc + 3][l])};
        *(uint2*)(Xt + ((size_t)b * 1024 + l0 + l) * 512 + c0 + cc) = *(const uint2*)o;
    }
}

// ---------------------------------------------------------------------------
// Kernel 3: QKV MFMA GEMM, 128x128 tile, BK=32, global_load_lds staging,
// double-buffered (2 x 16 KB), ONE barrier per K-step: loads for tile k+1
// issued right after the barrier, in flight across the whole compute phase,
// drained by the next barrier (m97's verified schedule). Linear LDS [128][32].
//   m-tiles 0-3 -> Qt[b][h][l][d], 4-7 -> Kt[b][h][m][d], 8-11 -> Vb[b][d][l]
// ---------------------------------------------------------------------------
__global__ __launch_bounds__(256) void mfma_qkv_kernel(
    const bf16* __restrict__ W,     // [1536,512]
    const bf16* __restrict__ Xt,    // [16,1024,512]
    const float* __restrict__ bias, // [1536]
    bf16* __restrict__ Qt,          // [16,4,1024,128]
    bf16* __restrict__ Kt,          // [16,4,1024,128]
    bf16* __restrict__ Vb)          // [16,512,1024]
{
    const int n0 = blockIdx.x * 128;
    const int m0 = blockIdx.y * 128;
    const int b  = blockIdx.z;
    const int t  = threadIdx.x;
    const int w  = t >> 6, lane = t & 63;
    const int c  = lane & 15, quad = lane >> 4;
    const int w0 = w & 1, w1 = w >> 1;
    const int ak = quad * 8;

    // dbuf: [A0 4096][B0 4096][A1 4096][B1 4096] els = 32 KB; Cs overlays
    __shared__ __align__(16) bf16 smem[17408];
    bf16* Cs = smem;                // [128][136] epilogue

    const bf16* Ag = W + (size_t)m0 * 512;
    const bf16* Bg = Xt + ((size_t)b * 1024 + n0) * 512;

    f32x4 acc[4][4];
    #pragma unroll
    for (int i = 0; i < 4; i++)
        #pragma unroll
        for (int j = 0; j < 4; j++)
            #pragma unroll
            for (int r = 0; r < 4; r++) acc[i][j][r] = 0.f;

    // prologue: stage tile 0 into buffer 0
    stage_tile_gld(Ag, smem, t);
    stage_tile_gld(Bg, smem + 4096, t);

    int cur = 0;
    for (int k0 = 0; k0 < 512; k0 += 32) {
        __syncthreads();    // drains gld (vmcnt 0) -> buf[cur] ready; prev
                            // iter's frag reads of buf[cur^1] done
        if (k0 + 32 < 512) {
            bf16* nb = smem + (cur ^ 1) * 8192;
            stage_tile_gld(Ag + k0 + 32, nb, t);
            stage_tile_gld(Bg + k0 + 32, nb + 4096, t);
        }
        const bf16* As = smem + cur * 8192;
        const bf16* Bs = As + 4096;
        short8 af[4], bfr[4];
        #pragma unroll
        for (int jm = 0; jm < 4; jm++)
            af[jm] = *(const short8*)&As[(w0 * 64 + jm * 16 + c) * 32 + ak];
        #pragma unroll
        for (int jn = 0; jn < 4; jn++)
            bfr[jn] = *(const short8*)&Bs[(w1 * 64 + jn * 16 + c) * 32 + ak];
        #pragma unroll
        for (int jm = 0; jm < 4; jm++)
            #pragma unroll
            for (int jn = 0; jn < 4; jn++)
                acc[jm][jn] = __builtin_amdgcn_mfma_f32_16x16x32_bf16(
                    af[jm], bfr[jn], acc[jm][jn], 0, 0, 0);
        cur ^= 1;
    }

    __syncthreads();
    const int cls = m0 >> 9;        // 0=Q, 1=K, 2=V
    if (cls < 2) {
        #pragma unroll
        for (int jm = 0; jm < 4; jm++) {
            #pragma unroll
            for (int jn = 0; jn < 4; jn++) {
                bf16 o4[4];
                #pragma unroll
                for (int r = 0; r < 4; r++) {
                    int orow = w0 * 64 + jm * 16 + quad * 4 + r;
                    o4[r] = f2b(acc[jm][jn][r] + bias[m0 + orow]);
                }
                *(uint2*)&Cs[(size_t)(w1 * 64 + jn * 16 + c) * 136
                             + w0 * 64 + jm * 16 + quad * 4] = *(const uint2*)o4;
            }
        }
        __syncthreads();
        const int head = (m0 >> 7) & 3;
        bf16* Db = (cls == 0 ? Qt : Kt)
                   + (((size_t)(b * 4 + head)) * 1024 + n0) * 128;
        for (int i = t; i < 2048; i += 256) {
            int row = i >> 4, ch = (i & 15) * 8;
            *(short8*)(Db + (size_t)row * 128 + ch) = *(const short8*)&Cs[row * 136 + ch];
        }
    } else {
        #pragma unroll
        for (int jm = 0; jm < 4; jm++) {
            #pragma unroll
            for (int r = 0; r < 4; r++) {
                int orow = w0 * 64 + jm * 16 + quad * 4 + r;
                float bs = bias[m0 + orow];
                #pragma unroll
                for (int jn = 0; jn < 4; jn++)
                    Cs[orow * 136 + w1 * 64 + jn * 16 + c] = f2b(acc[jm][jn][r] + bs);
            }
        }
        __syncthreads();
        bf16* Cb = Vb + ((size_t)b * 512 + (m0 - 1024)) * 1024 + n0;
        for (int i = t; i < 2048; i += 256) {
            int row = i >> 4, ch = (i & 15) * 8;
            *(short8*)(Cb + (size_t)row * 1024 + ch) = *(const short8*)&Cs[row * 136 + ch];
        }
    }
}

// ---------------------------------------------------------------------------
// Kernel 4: MFMA flash attention (round-11 verified: 50.1 us, VGPR 120).
// QT=256, 512 threads / 8 waves, 1 block/CU; swap23 K staging, in-reg P.
// ---------------------------------------------------------------------------
#define HD 128
#define QT 256
#define MT 64

__global__ __launch_bounds__(512, 2) void attn_mfma_kernel(
    const bf16* __restrict__ Qt,    // [16,4,1024,128]
    const bf16* __restrict__ Kt,    // [16,4,1024,128]
    const bf16* __restrict__ Vb,    // [16,512,1024]
    bf16* __restrict__ out)         // [16,1024,512]
{
    const int bh = blockIdx.x;      // 0..63
    const int qt = blockIdx.y;      // 0..3
    const int b = bh >> 2, h = bh & 3;
    const int t = threadIdx.x;      // 0..511
    const int w = t >> 6, lane = t & 63;   // w = 0..7
    const int wrow = lane & 31;
    const int blk  = lane >> 5;
    const int l0 = qt * QT;

    // 69632 B: loop Ks[64][136]+Vs[128][72] = 35840 B; epilogue Os[256][136]
    __shared__ __align__(16) bf16 smem[34816];

    // Q fragments: wave w owns q-rows [w*32, w*32+32) of this 256-row block
    const int qrow = w * 32 + wrow;
    const bf16* Qr = Qt + (((size_t)(b * 4 + h)) * 1024 + l0 + qrow) * 128;
    short8 aq[8];
    #pragma unroll
    for (int kt = 0; kt < 8; kt++)
        aq[kt] = *(const short8*)(Qr + kt * 16 + blk * 8);

    const bf16* Kb = Kt + (((size_t)(b * 4 + h)) * 1024) * 128;
    const bf16* Vg = Vb + ((size_t)(b * 512 + h * HD)) * 1024;

    bf16* Ks = smem;            // [64][136]
    bf16* Vs = smem + 8704;     // [128][72]

    short8 kreg[2], vreg[2];
    #pragma unroll
    for (int p = 0; p < 2; p++) {
        int i = t + p * 512;
        kreg[p] = *(const short8*)(Kb + (size_t)(i >> 4) * 128 + (i & 15) * 8);
        vreg[p] = *(const short8*)(Vg + (size_t)(i >> 3) * 1024 + (i & 7) * 8);
    }

    f32x16 acc_o[4];
    #pragma unroll
    for (int n = 0; n < 4; n++)
        #pragma unroll
        for (int r = 0; r < 16; r++) acc_o[n][r] = 0.f;

    float psl4[4] = {0.f, 0.f, 0.f, 0.f};

    // exp(s*scale - 6) = exp2(s*kSc - kSh)
    const float kSc = 0.08838834764831845f * 1.4426950408889634f;
    const float kSh = 6.0f * 1.4426950408889634f;

    for (int mt = 0; mt < 1024 / MT; mt++) {
        __syncthreads();    // prev iter's LDS reads done
        #pragma unroll
        for (int p = 0; p < 2; p++) {
            int i = t + p * 512;
            int m = i >> 4;
            int mrow = (m & 51) | ((m & 4) << 1) | ((m & 8) >> 1);   // swap bits 2,3
            *(short8*)&Ks[mrow * 136 + (i & 15) * 8] = kreg[p];
            *(short8*)&Vs[(i >> 3) * 72 + (i & 7) * 8]  = vreg[p];
        }
        __syncthreads();    // LDS visible

        {   // prefetch next tile (wraps harmlessly on last iter)
            int m0n = (mt < 15) ? (mt + 1) * MT : 0;
            #pragma unroll
            for (int p = 0; p < 2; p++) {
                int i = t + p * 512;
                kreg[p] = *(const short8*)(Kb + (size_t)(m0n + (i >> 4)) * 128 + (i & 15) * 8);
                vreg[p] = *(const short8*)(Vg + (size_t)(i >> 3) * 1024 + m0n + (i & 7) * 8);
            }
        }

        // ---- S^T = K Q^T : 2 m-tiles (32 each) x 8 k-steps
        f32x16 accs[2];
        #pragma unroll
        for (int n = 0; n < 2; n++)
            #pragma unroll
            for (int r = 0; r < 16; r++) accs[n][r] = 0.f;
        __builtin_amdgcn_s_setprio(1);
        #pragma unroll
        for (int kt = 0; kt < 8; kt++) {
            #pragma unroll
            for (int nt = 0; nt < 2; nt++) {
                short8 afr = *(const short8*)&Ks[(nt * 32 + wrow) * 136 + kt * 16 + blk * 8];
                accs[nt] = __builtin_amdgcn_mfma_f32_32x32x16_bf16(afr, aq[kt], accs[nt], 0, 0, 0);
            }
        }
        __builtin_amdgcn_s_setprio(0);

        // ---- softmax numerator, packed to bf16 PV fragments in-register
        unsigned pw[2][8];
        #pragma unroll
        for (int nt = 0; nt < 2; nt++) {
            float pv[16];
            #pragma unroll
            for (int r = 0; r < 16; r++)
                pv[r] = exp2f(accs[nt][r] * kSc - kSh);
            #pragma unroll
            for (int r = 0; r < 16; r++) psl4[r & 3] += pv[r];
            #pragma unroll
            for (int wd = 0; wd < 8; wd++)
                pw[nt][wd] = cvt_pk_bf16(pv[2 * wd], pv[2 * wd + 1]);
        }

        // ---- PV: O += P V^T (P fragments direct from regs)
        __builtin_amdgcn_s_setprio(1);
        #pragma unroll
        for (int kt2 = 0; kt2 < 4; kt2++) {
            union { short8 s; unsigned u[4]; } pa;
            #pragma unroll
            for (int wd = 0; wd < 4; wd++)
                pa.u[wd] = pw[kt2 >> 1][(kt2 & 1) * 4 + wd];
            #pragma unroll
            for (int nt2 = 0; nt2 < 4; nt2++) {
                short8 bv = *(const short8*)&Vs[(nt2 * 32 + wrow) * 72 + kt2 * 16 + blk * 8];
                acc_o[nt2] = __builtin_amdgcn_mfma_f32_32x32x16_bf16(pa.s, bv, acc_o[nt2], 0, 0, 0);
            }
        }
        __builtin_amdgcn_s_setprio(0);
    }

    // ---- epilogue: per-q totals live at lane wrow=q (both halves after xor)
    float psl = (psl4[0] + psl4[1]) + (psl4[2] + psl4[3]);
    float tot = psl + __shfl_xor(psl, 32);
    float inv[16];
    #pragma unroll
    for (int r = 0; r < 16; r++) {
        int q = (r & 3) + 8 * (r >> 2) + 4 * blk;
        inv[r] = __builtin_amdgcn_rcpf(__shfl(tot, q | (lane & 32)));
    }

    __syncthreads();                    // last iter's Ks/Vs reads done (all waves)
    bf16* Os = smem;                    // [256][136] = 69632 B
    #pragma unroll
    for (int nt2 = 0; nt2 < 4; nt2++)
        #pragma unroll
        for (int r = 0; r < 16; r++) {
            int row = w * 32 + (r & 3) + 8 * (r >> 2) + 4 * blk;
            Os[row * 136 + nt2 * 32 + wrow] = f2b(acc_o[nt2][r] * inv[r]);
        }
    __syncthreads();
    bf16* Ob = out + ((size_t)b * 1024 + l0) * 512 + h * HD;
    for (int i = t; i < 4096; i += 512) {
        int row = i >> 4, ch = (i & 15) * 8;
        *(short8*)(Ob + (size_t)row * 512 + ch) = *(const short8*)&Os[row * 136 + ch];
    }
}

// ---------------------------------------------------------------------------
// Kernel 5: proj GEMM + bias + residual, f32 out. Same gld double-buffered
// BK=32 one-barrier structure as qkv, linear LDS.
// ---------------------------------------------------------------------------
__global__ __launch_bounds__(256) void mfma_proj_kernel(
    const bf16* __restrict__ W,     // [512,512]
    const bf16* __restrict__ Xt,    // [16,1024,512] (attn_t)
    const float* __restrict__ bias, // [512]
    const float* __restrict__ res,  // [16,512,1024]
    float* __restrict__ C)          // [16,512,1024]
{
    const int n0 = blockIdx.x * 128;
    const int m0 = blockIdx.y * 128;
    const int b  = blockIdx.z;
    const int t  = threadIdx.x;
    const int w  = t >> 6, lane = t & 63;
    const int c  = lane & 15, quad = lane >> 4;
    const int w0 = w & 1, w1 = w >> 1;
    const int ak = quad * 8;

    __shared__ __align__(16) bf16 smem[17408];
    bf16* Cs = smem;

    const bf16* Ag = W + (size_t)m0 * 512;
    const bf16* Bg = Xt + ((size_t)b * 1024 + n0) * 512;

    f32x4 acc[4][4];
    #pragma unroll
    for (int i = 0; i < 4; i++)
        #pragma unroll
        for (int j = 0; j < 4; j++)
            #pragma unroll
            for (int r = 0; r < 4; r++) acc[i][j][r] = 0.f;

    stage_tile_gld(Ag, smem, t);
    stage_tile_gld(Bg, smem + 4096, t);

    int cur = 0;
    for (int k0 = 0; k0 < 512; k0 += 32) {
        __syncthreads();
        if (k0 + 32 < 512) {
            bf16* nb = smem + (cur ^ 1) * 8192;
            stage_tile_gld(Ag + k0 + 32, nb, t);
            stage_tile_gld(Bg + k0 + 32, nb + 4096, t);
        }
        const bf16* As = smem + cur * 8192;
        const bf16* Bs = As + 4096;
        short8 af[4], bfr[4];
        #pragma unroll
        for (int jm = 0; jm < 4; jm++)
            af[jm] = *(const short8*)&As[(w0 * 64 + jm * 16 + c) * 32 + ak];
        #pragma unroll
        for (int jn = 0; jn < 4; jn++)
            bfr[jn] = *(const short8*)&Bs[(w1 * 64 + jn * 16 + c) * 32 + ak];
        #pragma unroll
        for (int jm = 0; jm < 4; jm++)
            #pragma unroll
            for (int jn = 0; jn < 4; jn++)
                acc[jm][jn] = __builtin_amdgcn_mfma_f32_16x16x32_bf16(
                    af[jm], bfr[jn], acc[jm][jn], 0, 0, 0);
        cur ^= 1;
    }

    __syncthreads();
    #pragma unroll
    for (int jm = 0; jm < 4; jm++) {
        #pragma unroll
        for (int r = 0; r < 4; r++) {
            int orow = w0 * 64 + jm * 16 + quad * 4 + r;
            float bs = bias[m0 + orow];
            #pragma unroll
            for (int jn = 0; jn < 4; jn++)
                Cs[orow * 136 + w1 * 64 + jn * 16 + c] = f2b(acc[jm][jn][r] + bs);
        }
    }
    __syncthreads();
    const float* Rb = res + ((size_t)b * 512 + m0) * 1024 + n0;
    float* Cb = C + ((size_t)b * 512 + m0) * 1024 + n0;
    for (int i = t; i < 4096; i += 256) {
        int row = i >> 5, ch = (i & 31) * 4;
        float4 rv = *(const float4*)(Rb + (size_t)row * 1024 + ch);
        float4 ov;
        ov.x = b2f(Cs[row * 136 + ch + 0]) + rv.x;
        ov.y = b2f(Cs[row * 136 + ch + 1]) + rv.y;
        ov.z = b2f(Cs[row * 136 + ch + 2]) + rv.z;
        ov.w = b2f(Cs[row * 136 + ch + 3]) + rv.w;
        *(float4*)(Cb + (size_t)row * 1024 + ch) = ov;
    }
}

// ---------------------------------------------------------------------------
extern "C" void kernel_launch(void* const* d_in, const int* in_sizes, int n_in,
                              void* d_out, int out_size, void* d_ws, size_t ws_size,
                              hipStream_t stream)
{
    const float* x      = (const float*)d_in[0];
    const float* gamma  = (const float*)d_in[1];
    const float* beta   = (const float*)d_in[2];
    const float* w_qkv  = (const float*)d_in[3];
    const float* b_qkv  = (const float*)d_in[4];
    const float* w_proj = (const float*)d_in[5];
    const float* b_proj = (const float*)d_in[6];
    float* out = (float*)d_out;

    char* ws = (char*)d_ws;
    bf16*  wqb    = (bf16*)(ws + 65536);                      // 1.5 MB
    bf16*  wpb    = (bf16*)(ws + 65536 + 1572864);            // 0.5 MB
    char*  big    = ws + 65536 + 2097152;
    bf16*  Xt     = (bf16*)(big);                             // 16 MB [16,1024,512]
    bf16*  Qt     = (bf16*)(big + (size_t)16777216);          // 16 MB [16,4,1024,128]
    bf16*  Kt     = (bf16*)(big + (size_t)2 * 16777216);      // 16 MB
    bf16*  Vb     = (bf16*)(big + (size_t)3 * 16777216);      // 16 MB [16,512,1024]
    float* partS  = (float*)(big + (size_t)4 * 16777216);     // 2 KB
    float* partQ  = partS + 512;                              // 2 KB
    bf16*  attn_t = Xt;   // Xt dead after qkv GEMM; attention writes here

    hipLaunchKernelGGL(pre_kernel, dim3(1536), dim3(256), 0, stream,
                       w_qkv, w_proj, wqb, wpb, x, partS, partQ);
    hipLaunchKernelGGL(gn_apply_t_kernel, dim3(16, 8, 16), dim3(256), 0, stream,
                       x, partS, partQ, gamma, beta, Xt);
    hipLaunchKernelGGL(mfma_qkv_kernel, dim3(8, 12, 16), dim3(256), 0, stream,
                       wqb, Xt, b_qkv, Qt, Kt, Vb);
    hipLaunchKernelGGL(attn_mfma_kernel, dim3(64, 4), dim3(512), 0, stream,
                       Qt, Kt, Vb, attn_t);
    hipLaunchKernelGGL(mfma_proj_kernel, dim3(8, 4, 16), dim3(256), 0, stream,
                       wpb, attn_t, b_proj, x, out);
}